// Round 1
// baseline (165.288 us; speedup 1.0000x reference)
//
#include <hip/hip_runtime.h>

// y = (x + pe) * keep / 0.9
// pe[s,d] = sin(s / 10000^(2d/D)) if d even else cos(...)
// B=8, S=4096, D=512 -> 16,777,216 fp32 elements. Memory-bound (192 MiB traffic).

static constexpr float KEEP_SCALE = 1.0f / 0.9f;          // 1/(1-p)
static constexpr float INV_2PI    = 0.15915494309189535f; // 1/(2*pi)
// 10000^(-2/512)
static constexpr float RATIO      = 0.96466155f;
// -(2/512) * log2(10000)
static constexpr float C_LOG2     = -0.05190512648261547f;

__device__ __forceinline__ float sin_rev(float a) {
    float r = a * INV_2PI;
    r -= floorf(r);                       // range-reduce to [0,1) revolutions
    return __builtin_amdgcn_sinf(r);      // v_sin_f32: input in revolutions
}
__device__ __forceinline__ float cos_rev(float a) {
    float r = a * INV_2PI;
    r -= floorf(r);
    return __builtin_amdgcn_cosf(r);      // v_cos_f32: input in revolutions
}

__global__ __launch_bounds__(256) void pe_dropout_kernel(
    const float4* __restrict__ x,
    const float4* __restrict__ m,
    float4* __restrict__ o,
    int total4)
{
    int idx = blockIdx.x * 256 + threadIdx.x;
    if (idx >= total4) return;

    int e = idx << 2;                 // flat element index of .x component
    int d = e & 511;                  // D = 512
    float s = (float)((e >> 9) & 4095); // S = 4096 (shift by log2(D)=9, mask S-1)

    // inv_i = 10000^(-2*(d+i)/512); chain multiplies instead of 4 exp2's
    float inv0 = exp2f(C_LOG2 * (float)d);
    float inv1 = inv0 * RATIO;
    float inv2 = inv1 * RATIO;
    float inv3 = inv2 * RATIO;

    // d is a multiple of 4 -> lanes are [even, odd, even, odd] -> [sin, cos, sin, cos]
    float pe0 = sin_rev(s * inv0);
    float pe1 = cos_rev(s * inv1);
    float pe2 = sin_rev(s * inv2);
    float pe3 = cos_rev(s * inv3);

    float4 xv = x[idx];
    float4 mv = m[idx];

    float4 yv;
    yv.x = (xv.x + pe0) * (mv.x >= 0.1f ? KEEP_SCALE : 0.0f);
    yv.y = (xv.y + pe1) * (mv.y >= 0.1f ? KEEP_SCALE : 0.0f);
    yv.z = (xv.z + pe2) * (mv.z >= 0.1f ? KEEP_SCALE : 0.0f);
    yv.w = (xv.w + pe3) * (mv.w >= 0.1f ? KEEP_SCALE : 0.0f);

    o[idx] = yv;
}

extern "C" void kernel_launch(void* const* d_in, const int* in_sizes, int n_in,
                              void* d_out, int out_size, void* d_ws, size_t ws_size,
                              hipStream_t stream) {
    const float* x = (const float*)d_in[0];
    const float* m = (const float*)d_in[1];
    float* out = (float*)d_out;

    int n = in_sizes[0];          // 16,777,216 (divisible by 4)
    int total4 = n >> 2;          // 4,194,304 float4's
    int blocks = (total4 + 255) / 256;

    pe_dropout_kernel<<<blocks, 256, 0, stream>>>(
        (const float4*)x, (const float4*)m, (float4*)out, total4);
}